// Round 1
// baseline (490.571 us; speedup 1.0000x reference)
//
#include <hip/hip_runtime.h>
#include <hip/hip_bf16.h>
#include <stdint.h>

// ---------------------------------------------------------------------------
// LBConv: y = fc(relu(conv3x3_ternary(x))) + b
//   x        : [32][256][56][56] f32
//   binary_w : [512][256][3][3]  f32 (ternary)
//   fc_w     : [256][512]        f32
//   fc_b     : [256]             f32
//   out      : [32][256][56][56] f32
//
// R3 changes vs R2 (481us total; conv1 249us @ MfmaUtil 49%):
//  - k_conv1 rewritten to the 256x256 / BK=64 / 8-wave / 128KiB-LDS 8-phase
//    schedule (learn_hip m201 template): double-buffered LDS, per-phase
//    {12 ds_read_b128 -> 2 global_load_lds -> s_barrier -> setprio+16 MFMA
//    -> s_barrier}, counted s_waitcnt vmcnt(4)/vmcnt(2) (never 0 in loop)
//    so staging loads stay in flight across barriers. Halves L2 staging
//    traffic (4.13GB -> 2.02GB) vs the 128^2 tile.
//  - Grid 896: xcd=id&7 owns contiguous nt range, mt fastest (both cmblk
//    pairs of one nt share Xp reads on the same XCD L2).
//  - conv2/preps unchanged for attribution.
// ---------------------------------------------------------------------------

typedef __attribute__((ext_vector_type(8))) short short8;
typedef __attribute__((ext_vector_type(4))) float floatx4;

#define ROWE 8192            // elems per padded row per (b,cg): 16*64*8
#define NT_PER_B 28          // 3584/128 (old 2-row ntiles, still used by conv2)

// workspace byte offsets
#define OFF_WP  0            // 9*2*512*128*2        = 2,359,296
#define OFF_A2  2359296      // 4*2*128*128*2        =   262,144
#define OFF_XP  2621440      // 64*58*8192*2         = 60,817,408
#define OFF_Y   63439872     // 896*4*16384*2        = 117,440,512
// total required ws: 180,880,384 bytes (~173 MB)

__device__ static inline void async16(const void* gptr, void* lptr) {
  __builtin_amdgcn_global_load_lds(
      (const __attribute__((address_space(1))) void*)gptr,
      (__attribute__((address_space(3))) void*)lptr,
      16, 0, 0);
}

__device__ static inline unsigned short f2bf(float x) {
  __hip_bfloat16 h = __float2bfloat16(x);
  return *reinterpret_cast<unsigned short*>(&h);
}

// ---------------- prep: x (NCHW f32) -> Xp[b*2+cg][h'58][khi16][w'64][klo8] bf16
__global__ void k_xprep(const float* __restrict__ x, __hip_bfloat16* __restrict__ Xp) {
  const int t = blockIdx.x * 256 + threadIdx.x;
  const int wq  = t & 63;
  const int khi = (t >> 6) & 15;
  const int t2  = t >> 10;                               // bc*58 + hp
  const int hp  = t2 % 58;
  const int bc  = t2 / 58;
  const int b   = bc >> 1;
  const int cin0 = ((bc & 1) << 7) + (khi << 3);
  const int h = hp - 1, w = wq - 1;
  unsigned short v[8];
  if ((unsigned)h < 56u && (unsigned)w < 56u) {
    const float* xp = x + ((size_t)(b * 256 + cin0) * 56 + h) * 56 + w;
#pragma unroll
    for (int j = 0; j < 8; ++j) v[j] = f2bf(xp[(size_t)j * 3136]);
  } else {
#pragma unroll
    for (int j = 0; j < 8; ++j) v[j] = 0;
  }
  uint4 pk;
  pk.x = (unsigned)v[0] | ((unsigned)v[1] << 16);
  pk.y = (unsigned)v[2] | ((unsigned)v[3] << 16);
  pk.z = (unsigned)v[4] | ((unsigned)v[5] << 16);
  pk.w = (unsigned)v[6] | ((unsigned)v[7] << 16);
  *(uint4*)(Xp + (size_t)t * 8) = pk;
}

// ---------------- prep: binary_w -> Wp[tap9][cg2][cmblk4][cmh2][khi16][cml64][klo8]
__global__ void k_wprep(const float* __restrict__ bw, __hip_bfloat16* __restrict__ Wp) {
  const int idx = blockIdx.x * 256 + threadIdx.x;        // < 1,179,648 exact
  const int klo = idx & 7;
  const int cml = (idx >> 3) & 63;
  const int khi = (idx >> 9) & 15;
  const int cmh = (idx >> 13) & 1;
  const int rest = idx >> 14;                            // (tap*2+cg)*4 + cmblk
  const int cmblk = rest & 3;
  const int tcg = rest >> 2;
  const int cg  = tcg & 1;
  const int tap = tcg >> 1;
  const int kh = tap / 3, kw = tap - kh * 3;
  const int cm  = (cmblk << 7) + (cmh << 6) + cml;
  const int cin = (cg << 7) + (khi << 3) + klo;
  Wp[idx] = __float2bfloat16(bw[((cm * 256 + cin) * 3 + kh) * 3 + kw]);
}

// ---------------- prep: fc_w -> A2[cg4][mtile2][ch2][khi16][cl64][klo8]
__global__ void k_a2prep(const float* __restrict__ fw, __hip_bfloat16* __restrict__ A2) {
  const int idx = blockIdx.x * 256 + threadIdx.x;        // < 131,072 exact
  const int klo = idx & 7;
  const int cl  = (idx >> 3) & 63;
  const int khi = (idx >> 9) & 15;
  const int ch  = (idx >> 13) & 1;
  const int rest = idx >> 14;                            // cg*2 + mtile
  const int mtile = rest & 1;
  const int cg = rest >> 1;
  const int cout = (mtile << 7) + (ch << 6) + cl;
  const int cm   = (cg << 7) + (khi << 3) + klo;
  A2[idx] = __float2bfloat16(fw[cout * 512 + cm]);
}

// ---------------- conv1: 256x256-tile 8-phase schedule ----------------------
// Block (mt, nt): cmid [mt*256, mt*256+256), output rows [h0, h0+4), 64 w.
// K = 18 chunks (tap,cg) x 128 = 36 K-steps of BK=64.
// LDS 128KiB: buf{0,1} x { A[4 chunks of 8KB: (cb=wm,cmh)] , B[4 rows x 8KB] }.
// 8 waves: wm=wv>>2 picks cmblk within pair, wn=wv&3 picks output row.
// Per-wave output 128x64 -> acc[8][4] (128 VGPR).

#define SB0 __builtin_amdgcn_sched_barrier(0)
#define BARRIER do { SB0; __builtin_amdgcn_s_barrier(); SB0; } while (0)
#define MM(A, B, C) __builtin_amdgcn_mfma_f32_16x16x32_bf16((A), (B), (C), 0, 0, 0)
#define LD8(P) (*(const short8*)(P))

#define MFMA16(MIH, NIH) do { \
  __builtin_amdgcn_s_setprio(1); \
  acc[(MIH)*4+0][(NIH)*2+0] = MM(a0, b0, acc[(MIH)*4+0][(NIH)*2+0]); \
  acc[(MIH)*4+1][(NIH)*2+0] = MM(a1, b0, acc[(MIH)*4+1][(NIH)*2+0]); \
  acc[(MIH)*4+2][(NIH)*2+0] = MM(a2, b0, acc[(MIH)*4+2][(NIH)*2+0]); \
  acc[(MIH)*4+3][(NIH)*2+0] = MM(a3, b0, acc[(MIH)*4+3][(NIH)*2+0]); \
  acc[(MIH)*4+0][(NIH)*2+1] = MM(a0, b1, acc[(MIH)*4+0][(NIH)*2+1]); \
  acc[(MIH)*4+1][(NIH)*2+1] = MM(a1, b1, acc[(MIH)*4+1][(NIH)*2+1]); \
  acc[(MIH)*4+2][(NIH)*2+1] = MM(a2, b1, acc[(MIH)*4+2][(NIH)*2+1]); \
  acc[(MIH)*4+3][(NIH)*2+1] = MM(a3, b1, acc[(MIH)*4+3][(NIH)*2+1]); \
  acc[(MIH)*4+0][(NIH)*2+0] = MM(p0, b2, acc[(MIH)*4+0][(NIH)*2+0]); \
  acc[(MIH)*4+1][(NIH)*2+0] = MM(p1, b2, acc[(MIH)*4+1][(NIH)*2+0]); \
  acc[(MIH)*4+2][(NIH)*2+0] = MM(p2, b2, acc[(MIH)*4+2][(NIH)*2+0]); \
  acc[(MIH)*4+3][(NIH)*2+0] = MM(p3, b2, acc[(MIH)*4+3][(NIH)*2+0]); \
  acc[(MIH)*4+0][(NIH)*2+1] = MM(p0, b3, acc[(MIH)*4+0][(NIH)*2+1]); \
  acc[(MIH)*4+1][(NIH)*2+1] = MM(p1, b3, acc[(MIH)*4+1][(NIH)*2+1]); \
  acc[(MIH)*4+2][(NIH)*2+1] = MM(p2, b3, acc[(MIH)*4+2][(NIH)*2+1]); \
  acc[(MIH)*4+3][(NIH)*2+1] = MM(p3, b3, acc[(MIH)*4+3][(NIH)*2+1]); \
  __builtin_amdgcn_s_setprio(0); \
} while (0)

__global__ __launch_bounds__(512, 2) void k_conv1(
    const __hip_bfloat16* __restrict__ Xp, const __hip_bfloat16* __restrict__ Wp,
    __hip_bfloat16* __restrict__ Y) {
  __shared__ short8 lds_raw[8192];                       // 128 KiB
  char* lds = (char*)lds_raw;
  const int tid  = threadIdx.x;
  const int lane = tid & 63;
  const int wv   = tid >> 6;                             // 0..7
  const int wm   = wv >> 2;                              // 0..1 (cmblk within pair)
  const int wn   = wv & 3;                               // 0..3 (output row)
  const int l15  = lane & 15;
  const int quad = lane >> 4;
  const int id   = blockIdx.x;
  const int xcd  = id & 7;
  const int seq  = id >> 3;                              // 0..111
  const int mt   = seq & 1;
  const int nt   = xcd * 56 + (seq >> 1);                // 0..447
  const int b    = nt / 14;
  const int h0   = (nt % 14) * 4;

  const char* WpB = (const char*)Wp;
  const char* XpB = (const char*)Xp;

  // per-thread staging offset: r8=(wv&3)*2+q slices of 1KB, lane*16 within
  const int thrA = ((wv & 3) << 11) + lane * 16;
  // fragment read bases
  const int aRd = wm * 16384 + quad * 1024 + l15 * 16;   // + mih*8192 + kk*4096 + mi'*256
  const int bRd = wn * 8192 + quad * 1024 + l15 * 16;    // + nih*512 + kk*4096 + ni'*256

  floatx4 acc[8][4];
#pragma unroll
  for (int i = 0; i < 8; i++)
#pragma unroll
    for (int j = 0; j < 4; j++) acc[i][j] = (floatx4){0.f, 0.f, 0.f, 0.f};

  // ---- prologue: stage K-step 0 (t=0,cg=0,kh=0,kw=0,s=0) into buf0
  {
    const char* gA = WpB + (size_t)(2 * mt + wm) * 32768 + thrA;
    const char* gB = XpB + ((size_t)(b * 2) * 58 + h0 + wm) * 16384 + thrA;
    char* sA = lds + wm * 16384 + thrA;
    char* sB = lds + 32768 + wm * 8192 + thrA;
    async16(gA, sA);                     async16(gA + 1024, sA + 1024);          // A even (cmh0)
    async16(gB, sB);                     async16(gB + 1024, sB + 1024);          // B rows 0-1
    async16(gB + 32768, sB + 16384);     async16(gB + 32768 + 1024, sB + 16384 + 1024); // B rows 2-3
    async16(gA + 16384, sA + 8192);      async16(gA + 16384 + 1024, sA + 8192 + 1024);  // A odd (cmh1)
    asm volatile("s_waitcnt vmcnt(2)" ::: "memory");     // A-even,B0,B1 landed; A-odd in flight
    BARRIER;
  }

  // One K-step (BK=64): compute buf[BUF], stage next K-step into buf[BUF^1].
  // Stage order: A-even(ph0), B0(ph1), B1(ph2), A-odd(ph3). Counted waits:
  // vmcnt(4) end of ph1 (guarantees this step's A-odd), vmcnt(2) end of ph3
  // (guarantees next step's A-even,B0,B1). Never 0 except final drain.
  auto STEP = [&](int BUF, const char* gA, const char* gB, bool pred) {
    char* ldsC = lds + BUF * 65536;            // compute buffer
    char* ldsS = lds + (BUF ^ 1) * 65536;      // stage target
    const char* Ab = ldsC + aRd;
    const char* Bb = ldsC + 32768 + bRd;
    char* sA = ldsS + wm * 16384 + thrA;
    char* sB = ldsS + 32768 + wm * 8192 + thrA;
    short8 a0, a1, a2, a3, p0, p1, p2, p3, b0, b1, b2, b3;
    // ---- phase 0: (mih0, nih0)
    a0 = LD8(Ab + 0);     a1 = LD8(Ab + 256);  a2 = LD8(Ab + 512);  a3 = LD8(Ab + 768);
    p0 = LD8(Ab + 4096);  p1 = LD8(Ab + 4352); p2 = LD8(Ab + 4608); p3 = LD8(Ab + 4864);
    b0 = LD8(Bb + 0);     b1 = LD8(Bb + 256);  b2 = LD8(Bb + 4096); b3 = LD8(Bb + 4352);
    if (pred) { async16(gA, sA); async16(gA + 1024, sA + 1024); }
    BARRIER;
    MFMA16(0, 0);
    BARRIER;
    // ---- phase 1: (mih0, nih1)
    b0 = LD8(Bb + 512);   b1 = LD8(Bb + 768);  b2 = LD8(Bb + 4608); b3 = LD8(Bb + 4864);
    if (pred) { async16(gB, sB); async16(gB + 1024, sB + 1024); }
    BARRIER;
    MFMA16(0, 1);
    if (pred) asm volatile("s_waitcnt vmcnt(4)" ::: "memory");
    else      asm volatile("s_waitcnt vmcnt(0)" ::: "memory");
    BARRIER;
    // ---- phase 2: (mih1, nih0)
    a0 = LD8(Ab + 8192);  a1 = LD8(Ab + 8448);  a2 = LD8(Ab + 8704);  a3 = LD8(Ab + 8960);
    p0 = LD8(Ab + 12288); p1 = LD8(Ab + 12544); p2 = LD8(Ab + 12800); p3 = LD8(Ab + 13056);
    b0 = LD8(Bb + 0);     b1 = LD8(Bb + 256);   b2 = LD8(Bb + 4096);  b3 = LD8(Bb + 4352);
    if (pred) { async16(gB + 32768, sB + 16384); async16(gB + 32768 + 1024, sB + 16384 + 1024); }
    BARRIER;
    MFMA16(1, 0);
    BARRIER;
    // ---- phase 3: (mih1, nih1)
    b0 = LD8(Bb + 512);   b1 = LD8(Bb + 768);   b2 = LD8(Bb + 4608);  b3 = LD8(Bb + 4864);
    if (pred) { async16(gA + 16384, sA + 8192); async16(gA + 16384 + 1024, sA + 8192 + 1024); }
    BARRIER;
    MFMA16(1, 1);
    asm volatile("s_waitcnt vmcnt(2)" ::: "memory");
    BARRIER;
  };

  for (int t = 0; t < 18; ++t) {
    const int cg  = t & 1;
    const int tap = t >> 1;
    const int kh = tap / 3, kw = tap - kh * 3;
    const int tn   = t + 1;
    const int cgn  = tn & 1;
    const int tapn = tn >> 1;
    const int khn = tapn / 3, kwn = tapn - khn * 3;
    // stage ptrs for (t, s=1) [consumed by step B of this iter]:
    const char* gA1 = WpB + (size_t)(t * 4 + 2 * mt + wm) * 32768 + 8192 + thrA;
    const char* gB1 = XpB + ((size_t)(b * 2 + cg) * 58 + h0 + kh + wm) * 16384 + kw * 16 + 8192 + thrA;
    // stage ptrs for (t+1, s=0) [consumed by step A of next iter]:
    const char* gA0 = WpB + (size_t)(tn * 4 + 2 * mt + wm) * 32768 + thrA;
    const char* gB0 = XpB + ((size_t)(b * 2 + cgn) * 58 + h0 + khn + wm) * 16384 + kwn * 16 + thrA;
    STEP(0, gA1, gB1, true);       // compute j=2t   (buf0), stage (t,1) -> buf1
    STEP(1, gA0, gB0, t < 17);     // compute j=2t+1 (buf1), stage (t+1,0) -> buf0
  }

  // ---- epilogue: relu -> bf16 -> Y[ntile][cmblk][r2][khi16][w64][klo8]
  const int cmblk = mt * 2 + wm;
  const int ntile = nt * 2 + (wn >> 1);
  const int r2    = wn & 1;
  const size_t ybase = (((size_t)ntile * 4 + cmblk) * 2 + r2) * 8192;
#pragma unroll
  for (int mi = 0; mi < 8; ++mi) {
    const int cml  = mi * 16 + quad * 4;                 // + reg r (0..3)
    const int khi  = cml >> 3;
    const int klo0 = cml & 7;                            // 0 or 4
#pragma unroll
    for (int ni = 0; ni < 4; ++ni) {
      const int w = ni * 16 + l15;
      floatx4 f = acc[mi][ni];
      unsigned lo = (unsigned)f2bf(fmaxf(f[0], 0.f)) | ((unsigned)f2bf(fmaxf(f[1], 0.f)) << 16);
      unsigned hi = (unsigned)f2bf(fmaxf(f[2], 0.f)) | ((unsigned)f2bf(fmaxf(f[3], 0.f)) << 16);
      uint2 pk = make_uint2(lo, hi);
      *(uint2*)((char*)Y + (ybase + (size_t)khi * 512 + w * 8 + klo0) * 2) = pk;
    }
  }
}

// ---------------- conv2: out = fc_w * Y + b, mask w<56, store NCHW f32
__global__ __launch_bounds__(256, 2) void k_conv2(
    const __hip_bfloat16* __restrict__ Y, const __hip_bfloat16* __restrict__ A2,
    const float* __restrict__ fcb, float* __restrict__ out) {
  __shared__ short8 lds_raw[4096];
  char* lds = (char*)lds_raw;
  const int tid  = threadIdx.x;
  const int lane = tid & 63;
  const int wv   = tid >> 6;
  const int wm   = wv >> 1, wn = wv & 1;
  const int l15  = lane & 15;
  const int quad = lane >> 4;
  const int id   = blockIdx.x;
  const int xcd  = id & 7;
  const int seq  = id >> 3;                              // 0..223
  const int mtile = seq & 1;
  const int rp    = xcd * 112 + (seq >> 1);              // 0..895

  floatx4 acc[4][4];
#pragma unroll
  for (int i = 0; i < 4; i++)
#pragma unroll
    for (int j = 0; j < 4; j++) acc[i][j] = (floatx4){0.f, 0.f, 0.f, 0.f};

  for (int cg = 0; cg < 4; ++cg) {
    const size_t a_base = (size_t)(cg * 2 + mtile) * 16384;
    const size_t b_base = (size_t)(rp * 4 + cg) * 16384;
    __syncthreads();
    const char* gA = (const char*)(A2 + a_base) + wv * 8192 + lane * 16;
    const char* gB = (const char*)(Y + b_base) + wv * 8192 + lane * 16;
    char* lA = lds + wv * 8192;
    char* lB = lds + 32768 + wv * 8192;
#pragma unroll
    for (int c = 0; c < 8; ++c) {
      async16(gA + c * 1024, lA + c * 1024);
      async16(gB + c * 1024, lB + c * 1024);
    }
    __syncthreads();
#pragma unroll
    for (int kk = 0; kk < 4; ++kk) {
      short8 af[4], bf[4];
#pragma unroll
      for (int mi = 0; mi < 4; ++mi) {
        const int m = wm * 64 + mi * 16 + l15;
        af[mi] = *(const short8*)(lds + ((m >> 6) * 16 + kk * 4 + quad) * 1024 + (m & 63) * 16);
      }
#pragma unroll
      for (int ni = 0; ni < 4; ++ni) {
        const int n = wn * 64 + ni * 16 + l15;
        bf[ni] = *(const short8*)(lds + 32768 + ((n >> 6) * 16 + kk * 4 + quad) * 1024 + (n & 63) * 16);
      }
#pragma unroll
      for (int mi = 0; mi < 4; ++mi)
#pragma unroll
        for (int ni = 0; ni < 4; ++ni)
          acc[mi][ni] = __builtin_amdgcn_mfma_f32_16x16x32_bf16(af[mi], bf[ni], acc[mi][ni], 0, 0, 0);
    }
  }

  const int b   = rp / NT_PER_B;
  const int nb0 = (rp % NT_PER_B) * 128;
#pragma unroll
  for (int mi = 0; mi < 4; ++mi) {
    const int co = mtile * 128 + wm * 64 + mi * 16 + quad * 4;  // + reg r
#pragma unroll
    for (int ni = 0; ni < 4; ++ni) {
      const int n = wn * 64 + ni * 16 + l15;
      const int w = n & 63;
      if (w < 56) {
        const int nb = nb0 + n;
        const int h  = nb >> 6;
        floatx4 f = acc[mi][ni];
        const size_t base = (size_t)(b * 256 + co) * 3136 + h * 56 + w;
#pragma unroll
        for (int r = 0; r < 4; ++r)
          out[base + (size_t)r * 3136] = f[r] + fcb[co + r];
      }
    }
  }
}

extern "C" void kernel_launch(void* const* d_in, const int* in_sizes, int n_in,
                              void* d_out, int out_size, void* d_ws, size_t ws_size,
                              hipStream_t stream) {
  const float* x  = (const float*)d_in[0];
  const float* bw = (const float*)d_in[1];
  const float* fw = (const float*)d_in[2];
  const float* fb = (const float*)d_in[3];
  float* out = (float*)d_out;
  char* ws = (char*)d_ws;

  __hip_bfloat16* Wp = (__hip_bfloat16*)(ws + OFF_WP);
  __hip_bfloat16* A2 = (__hip_bfloat16*)(ws + OFF_A2);
  __hip_bfloat16* Xp = (__hip_bfloat16*)(ws + OFF_XP);
  __hip_bfloat16* Y  = (__hip_bfloat16*)(ws + OFF_Y);

  k_wprep<<<dim3(4608), dim3(256), 0, stream>>>(bw, Wp);
  k_a2prep<<<dim3(512), dim3(256), 0, stream>>>(fw, A2);
  k_xprep<<<dim3(14848), dim3(256), 0, stream>>>(x, Xp);
  k_conv1<<<dim3(896), dim3(512), 0, stream>>>(Xp, Wp, Y);
  k_conv2<<<dim3(1792), dim3(256), 0, stream>>>(Y, A2, fb, out);
}

// Round 2
// 485.410 us; speedup vs baseline: 1.0106x; 1.0106x over previous
//
#include <hip/hip_runtime.h>
#include <hip/hip_bf16.h>
#include <stdint.h>

// ---------------------------------------------------------------------------
// LBConv: y = fc(relu(conv3x3_ternary(x))) + b
//   x        : [32][256][56][56] f32
//   binary_w : [512][256][3][3]  f32 (ternary)
//   fc_w     : [256][512]        f32
//   fc_b     : [256]             f32
//   out      : [32][256][56][56] f32
//
// R4 changes vs R3 (490us total; conv1 278us @ MfmaUtil 42%):
//  - R3's 8-barrier-per-K-step schedule paid ~1200cyc/step of sync overhead
//    to hide HBM latency that doesn't exist here (L2-resident: FETCH 67MB).
//    New schedule: ONE s_barrier + ONE vmcnt(0) per K-step. All 8 staging
//    loads issued at step top (~3000cyc before the drain >> L2 latency);
//    4 MFMA quadrants in zigzag order Q(0,0)->Q(0,1)->Q(1,1)->Q(1,0) so
//    each B-half is reused across 2 consecutive quadrants: 28 ds_read_b128
//    per wave per step (was 32), still only 12 live fragments (no VGPR
//    growth). sched_barrier(0) fences between quadrants stop the compiler
//    hoisting reads (register-pressure guard).
//  - Correctness: per step j, stages write bufS=buf[(j+1)&1]; all ds_reads
//    of bufS (as step j-1's compute buf) completed before step j-1's
//    barrier (lgkmcnt precedes MFMA precedes barrier). vmcnt(0)+barrier at
//    step end guarantees ALL waves' staged data landed before step j+1.
//  - conv2/preps unchanged.
// ---------------------------------------------------------------------------

typedef __attribute__((ext_vector_type(8))) short short8;
typedef __attribute__((ext_vector_type(4))) float floatx4;

#define ROWE 8192            // elems per padded row per (b,cg): 16*64*8
#define NT_PER_B 28          // 3584/128 (old 2-row ntiles, still used by conv2)

// workspace byte offsets
#define OFF_WP  0            // 9*2*512*128*2        = 2,359,296
#define OFF_A2  2359296      // 4*2*128*128*2        =   262,144
#define OFF_XP  2621440      // 64*58*8192*2         = 60,817,408
#define OFF_Y   63439872     // 896*4*16384*2        = 117,440,512
// total required ws: 180,880,384 bytes (~173 MB)

__device__ static inline void async16(const void* gptr, void* lptr) {
  __builtin_amdgcn_global_load_lds(
      (const __attribute__((address_space(1))) void*)gptr,
      (__attribute__((address_space(3))) void*)lptr,
      16, 0, 0);
}

__device__ static inline unsigned short f2bf(float x) {
  __hip_bfloat16 h = __float2bfloat16(x);
  return *reinterpret_cast<unsigned short*>(&h);
}

// ---------------- prep: x (NCHW f32) -> Xp[b*2+cg][h'58][khi16][w'64][klo8] bf16
__global__ void k_xprep(const float* __restrict__ x, __hip_bfloat16* __restrict__ Xp) {
  const int t = blockIdx.x * 256 + threadIdx.x;
  const int wq  = t & 63;
  const int khi = (t >> 6) & 15;
  const int t2  = t >> 10;                               // bc*58 + hp
  const int hp  = t2 % 58;
  const int bc  = t2 / 58;
  const int b   = bc >> 1;
  const int cin0 = ((bc & 1) << 7) + (khi << 3);
  const int h = hp - 1, w = wq - 1;
  unsigned short v[8];
  if ((unsigned)h < 56u && (unsigned)w < 56u) {
    const float* xp = x + ((size_t)(b * 256 + cin0) * 56 + h) * 56 + w;
#pragma unroll
    for (int j = 0; j < 8; ++j) v[j] = f2bf(xp[(size_t)j * 3136]);
  } else {
#pragma unroll
    for (int j = 0; j < 8; ++j) v[j] = 0;
  }
  uint4 pk;
  pk.x = (unsigned)v[0] | ((unsigned)v[1] << 16);
  pk.y = (unsigned)v[2] | ((unsigned)v[3] << 16);
  pk.z = (unsigned)v[4] | ((unsigned)v[5] << 16);
  pk.w = (unsigned)v[6] | ((unsigned)v[7] << 16);
  *(uint4*)(Xp + (size_t)t * 8) = pk;
}

// ---------------- prep: binary_w -> Wp[tap9][cg2][cmblk4][cmh2][khi16][cml64][klo8]
__global__ void k_wprep(const float* __restrict__ bw, __hip_bfloat16* __restrict__ Wp) {
  const int idx = blockIdx.x * 256 + threadIdx.x;        // < 1,179,648 exact
  const int klo = idx & 7;
  const int cml = (idx >> 3) & 63;
  const int khi = (idx >> 9) & 15;
  const int cmh = (idx >> 13) & 1;
  const int rest = idx >> 14;                            // (tap*2+cg)*4 + cmblk
  const int cmblk = rest & 3;
  const int tcg = rest >> 2;
  const int cg  = tcg & 1;
  const int tap = tcg >> 1;
  const int kh = tap / 3, kw = tap - kh * 3;
  const int cm  = (cmblk << 7) + (cmh << 6) + cml;
  const int cin = (cg << 7) + (khi << 3) + klo;
  Wp[idx] = __float2bfloat16(bw[((cm * 256 + cin) * 3 + kh) * 3 + kw]);
}

// ---------------- prep: fc_w -> A2[cg4][mtile2][ch2][khi16][cl64][klo8]
__global__ void k_a2prep(const float* __restrict__ fw, __hip_bfloat16* __restrict__ A2) {
  const int idx = blockIdx.x * 256 + threadIdx.x;        // < 131,072 exact
  const int klo = idx & 7;
  const int cl  = (idx >> 3) & 63;
  const int khi = (idx >> 9) & 15;
  const int ch  = (idx >> 13) & 1;
  const int rest = idx >> 14;                            // cg*2 + mtile
  const int mtile = rest & 1;
  const int cg = rest >> 1;
  const int cout = (mtile << 7) + (ch << 6) + cl;
  const int cm   = (cg << 7) + (khi << 3) + klo;
  A2[idx] = __float2bfloat16(fw[cout * 512 + cm]);
}

// ---------------- conv1: 256x256-tile, 1-barrier-per-K-step schedule --------
// Block (mt, nt): cmid [mt*256, mt*256+256), output rows [h0, h0+4), 64 w.
// K = 36 steps of BK=64 (j = 2t+s; t = (tap,cg) chunk, s = khi half).
// LDS 128KiB: buf{0,1} x { A 32KB [wm:16KB][cmh:8KB] , B 32KB [4 rows x 8KB] }.
// 8 waves: wm=wv>>2 cmblk within pair, wn=wv&3 output row.
// Per-wave output 128x64 -> acc[8][4] (128 VGPR), 12 live frags.

#define SB0 __builtin_amdgcn_sched_barrier(0)
#define MM(A, B, C) __builtin_amdgcn_mfma_f32_16x16x32_bf16((A), (B), (C), 0, 0, 0)
#define LD8(P) (*(const short8*)(P))

// one quadrant: rows mih*4+0..3, cols nih*2+{0,1}; b0,b1 = kk0 cols, b2,b3 = kk1
#define MFMAQ(MIH, NIH) do { \
  __builtin_amdgcn_s_setprio(1); \
  acc[(MIH)*4+0][(NIH)*2+0] = MM(a0, b0, acc[(MIH)*4+0][(NIH)*2+0]); \
  acc[(MIH)*4+1][(NIH)*2+0] = MM(a1, b0, acc[(MIH)*4+1][(NIH)*2+0]); \
  acc[(MIH)*4+2][(NIH)*2+0] = MM(a2, b0, acc[(MIH)*4+2][(NIH)*2+0]); \
  acc[(MIH)*4+3][(NIH)*2+0] = MM(a3, b0, acc[(MIH)*4+3][(NIH)*2+0]); \
  acc[(MIH)*4+0][(NIH)*2+1] = MM(a0, b1, acc[(MIH)*4+0][(NIH)*2+1]); \
  acc[(MIH)*4+1][(NIH)*2+1] = MM(a1, b1, acc[(MIH)*4+1][(NIH)*2+1]); \
  acc[(MIH)*4+2][(NIH)*2+1] = MM(a2, b1, acc[(MIH)*4+2][(NIH)*2+1]); \
  acc[(MIH)*4+3][(NIH)*2+1] = MM(a3, b1, acc[(MIH)*4+3][(NIH)*2+1]); \
  acc[(MIH)*4+0][(NIH)*2+0] = MM(p0, b2, acc[(MIH)*4+0][(NIH)*2+0]); \
  acc[(MIH)*4+1][(NIH)*2+0] = MM(p1, b2, acc[(MIH)*4+1][(NIH)*2+0]); \
  acc[(MIH)*4+2][(NIH)*2+0] = MM(p2, b2, acc[(MIH)*4+2][(NIH)*2+0]); \
  acc[(MIH)*4+3][(NIH)*2+0] = MM(p3, b2, acc[(MIH)*4+3][(NIH)*2+0]); \
  acc[(MIH)*4+0][(NIH)*2+1] = MM(p0, b3, acc[(MIH)*4+0][(NIH)*2+1]); \
  acc[(MIH)*4+1][(NIH)*2+1] = MM(p1, b3, acc[(MIH)*4+1][(NIH)*2+1]); \
  acc[(MIH)*4+2][(NIH)*2+1] = MM(p2, b3, acc[(MIH)*4+2][(NIH)*2+1]); \
  acc[(MIH)*4+3][(NIH)*2+1] = MM(p3, b3, acc[(MIH)*4+3][(NIH)*2+1]); \
  __builtin_amdgcn_s_setprio(0); \
} while (0)

__global__ __launch_bounds__(512, 2) void k_conv1(
    const __hip_bfloat16* __restrict__ Xp, const __hip_bfloat16* __restrict__ Wp,
    __hip_bfloat16* __restrict__ Y) {
  __shared__ short8 lds_raw[8192];                       // 128 KiB
  char* lds = (char*)lds_raw;
  const int tid  = threadIdx.x;
  const int lane = tid & 63;
  const int wv   = tid >> 6;                             // 0..7
  const int wm   = wv >> 2;                              // 0..1 (cmblk within pair)
  const int wn   = wv & 3;                               // 0..3 (output row)
  const int l15  = lane & 15;
  const int quad = lane >> 4;
  const int id   = blockIdx.x;
  const int xcd  = id & 7;
  const int seq  = id >> 3;                              // 0..111
  const int mt   = seq & 1;
  const int nt   = xcd * 56 + (seq >> 1);                // 0..447
  const int b    = nt / 14;
  const int h0   = (nt % 14) * 4;

  const char* WpB = (const char*)Wp;
  const char* XpB = (const char*)Xp;

  // per-thread staging offset: (wv&3) slices of 2KB, lane*16 within
  const int thrA = ((wv & 3) << 11) + lane * 16;
  // fragment read bases
  const int aRd = wm * 16384 + quad * 1024 + l15 * 16;   // + mih*8192 + kk*4096 + mi*256
  const int bRd = wn * 8192 + quad * 1024 + l15 * 16;    // + ni*256 + kk*4096

  floatx4 acc[8][4];
#pragma unroll
  for (int i = 0; i < 8; i++)
#pragma unroll
    for (int j = 0; j < 4; j++) acc[i][j] = (floatx4){0.f, 0.f, 0.f, 0.f};

  // ---- prologue: stage K-step 0 (t=0: tap0,cg0 / s=0) into buf0
  {
    const char* gA = WpB + (size_t)(2 * mt + wm) * 32768 + thrA;
    const char* gB = XpB + ((size_t)(b * 2) * 58 + h0 + wm) * 16384 + thrA;
    char* sA = lds + wm * 16384 + thrA;
    char* sB = lds + 32768 + wm * 8192 + thrA;
    async16(gA, sA);                 async16(gA + 1024, sA + 1024);                  // A-even
    async16(gB, sB);                 async16(gB + 1024, sB + 1024);                  // B rows 0-1
    async16(gB + 32768, sB + 16384); async16(gB + 32768 + 1024, sB + 16384 + 1024); // B rows 2-3
    async16(gA + 16384, sA + 8192);  async16(gA + 16384 + 1024, sA + 8192 + 1024);  // A-odd
    SB0;
    asm volatile("s_waitcnt vmcnt(0)" ::: "memory");
    __builtin_amdgcn_s_barrier();
    SB0;
  }

  // one K-step: stage next step into buf[BUF^1] (all 8 loads up front),
  // compute buf[BUF] as 4 zigzag quadrants, single vmcnt(0)+barrier at end.
  auto STEP = [&](int BUF, const char* gA, const char* gB, bool pred) {
    char* ldsC = lds + BUF * 65536;            // compute buffer
    char* ldsS = lds + (BUF ^ 1) * 65536;      // stage target
    const char* Ab = ldsC + aRd;
    const char* Bb = ldsC + 32768 + bRd;
    char* sA = ldsS + wm * 16384 + thrA;
    char* sB = ldsS + 32768 + wm * 8192 + thrA;
    if (pred) {
      async16(gA, sA);                 async16(gA + 1024, sA + 1024);
      async16(gB, sB);                 async16(gB + 1024, sB + 1024);
      async16(gB + 32768, sB + 16384); async16(gB + 32768 + 1024, sB + 16384 + 1024);
      async16(gA + 16384, sA + 8192);  async16(gA + 16384 + 1024, sA + 8192 + 1024);
    }
    SB0;
    short8 a0, a1, a2, a3, p0, p1, p2, p3, b0, b1, b2, b3;
    // Q(0,0): A-even + B-nih0
    a0 = LD8(Ab + 0);     a1 = LD8(Ab + 256);   a2 = LD8(Ab + 512);   a3 = LD8(Ab + 768);
    p0 = LD8(Ab + 4096);  p1 = LD8(Ab + 4352);  p2 = LD8(Ab + 4608);  p3 = LD8(Ab + 4864);
    b0 = LD8(Bb + 0);     b1 = LD8(Bb + 256);   b2 = LD8(Bb + 4096);  b3 = LD8(Bb + 4352);
    MFMAQ(0, 0);
    SB0;
    // Q(0,1): reuse A-even, load B-nih1
    b0 = LD8(Bb + 512);   b1 = LD8(Bb + 768);   b2 = LD8(Bb + 4608);  b3 = LD8(Bb + 4864);
    MFMAQ(0, 1);
    SB0;
    // Q(1,1): load A-odd, reuse B-nih1
    a0 = LD8(Ab + 8192);  a1 = LD8(Ab + 8448);  a2 = LD8(Ab + 8704);  a3 = LD8(Ab + 8960);
    p0 = LD8(Ab + 12288); p1 = LD8(Ab + 12544); p2 = LD8(Ab + 12800); p3 = LD8(Ab + 13056);
    MFMAQ(1, 1);
    SB0;
    // Q(1,0): reuse A-odd, reload B-nih0
    b0 = LD8(Bb + 0);     b1 = LD8(Bb + 256);   b2 = LD8(Bb + 4096);  b3 = LD8(Bb + 4352);
    MFMAQ(1, 0);
    SB0;
    asm volatile("s_waitcnt vmcnt(0)" ::: "memory");
    __builtin_amdgcn_s_barrier();
    SB0;
  };

  for (int j = 0; j < 36; ++j) {
    const int jn   = j + 1;
    const int tn   = jn >> 1;                  // next step's (tap,cg) chunk
    const int sn   = jn & 1;                   // next step's khi half
    const int cgn  = tn & 1;
    const int tapn = tn >> 1;
    const int khn = tapn / 3, kwn = tapn - khn * 3;
    const char* gA = WpB + (size_t)(tn * 4 + 2 * mt + wm) * 32768 + sn * 8192 + thrA;
    const char* gB = XpB + ((size_t)(b * 2 + cgn) * 58 + h0 + khn + wm) * 16384
                     + kwn * 16 + sn * 8192 + thrA;
    STEP(j & 1, gA, gB, j < 35);
  }

  // ---- epilogue: relu -> bf16 -> Y[ntile][cmblk][r2][khi16][w64][klo8]
  const int cmblk = mt * 2 + wm;
  const int ntile = nt * 2 + (wn >> 1);
  const int r2    = wn & 1;
  const size_t ybase = (((size_t)ntile * 4 + cmblk) * 2 + r2) * 8192;
#pragma unroll
  for (int mi = 0; mi < 8; ++mi) {
    const int cml  = mi * 16 + quad * 4;                 // + reg r (0..3)
    const int khi  = cml >> 3;
    const int klo0 = cml & 7;                            // 0 or 4
#pragma unroll
    for (int ni = 0; ni < 4; ++ni) {
      const int w = ni * 16 + l15;
      floatx4 f = acc[mi][ni];
      unsigned lo = (unsigned)f2bf(fmaxf(f[0], 0.f)) | ((unsigned)f2bf(fmaxf(f[1], 0.f)) << 16);
      unsigned hi = (unsigned)f2bf(fmaxf(f[2], 0.f)) | ((unsigned)f2bf(fmaxf(f[3], 0.f)) << 16);
      uint2 pk = make_uint2(lo, hi);
      *(uint2*)((char*)Y + (ybase + (size_t)khi * 512 + w * 8 + klo0) * 2) = pk;
    }
  }
}

// ---------------- conv2: out = fc_w * Y + b, mask w<56, store NCHW f32
__global__ __launch_bounds__(256, 2) void k_conv2(
    const __hip_bfloat16* __restrict__ Y, const __hip_bfloat16* __restrict__ A2,
    const float* __restrict__ fcb, float* __restrict__ out) {
  __shared__ short8 lds_raw[4096];
  char* lds = (char*)lds_raw;
  const int tid  = threadIdx.x;
  const int lane = tid & 63;
  const int wv   = tid >> 6;
  const int wm   = wv >> 1, wn = wv & 1;
  const int l15  = lane & 15;
  const int quad = lane >> 4;
  const int id   = blockIdx.x;
  const int xcd  = id & 7;
  const int seq  = id >> 3;                              // 0..223
  const int mtile = seq & 1;
  const int rp    = xcd * 112 + (seq >> 1);              // 0..895

  floatx4 acc[4][4];
#pragma unroll
  for (int i = 0; i < 4; i++)
#pragma unroll
    for (int j = 0; j < 4; j++) acc[i][j] = (floatx4){0.f, 0.f, 0.f, 0.f};

  for (int cg = 0; cg < 4; ++cg) {
    const size_t a_base = (size_t)(cg * 2 + mtile) * 16384;
    const size_t b_base = (size_t)(rp * 4 + cg) * 16384;
    __syncthreads();
    const char* gA = (const char*)(A2 + a_base) + wv * 8192 + lane * 16;
    const char* gB = (const char*)(Y + b_base) + wv * 8192 + lane * 16;
    char* lA = lds + wv * 8192;
    char* lB = lds + 32768 + wv * 8192;
#pragma unroll
    for (int c = 0; c < 8; ++c) {
      async16(gA + c * 1024, lA + c * 1024);
      async16(gB + c * 1024, lB + c * 1024);
    }
    __syncthreads();
#pragma unroll
    for (int kk = 0; kk < 4; ++kk) {
      short8 af[4], bf[4];
#pragma unroll
      for (int mi = 0; mi < 4; ++mi) {
        const int m = wm * 64 + mi * 16 + l15;
        af[mi] = *(const short8*)(lds + ((m >> 6) * 16 + kk * 4 + quad) * 1024 + (m & 63) * 16);
      }
#pragma unroll
      for (int ni = 0; ni < 4; ++ni) {
        const int n = wn * 64 + ni * 16 + l15;
        bf[ni] = *(const short8*)(lds + 32768 + ((n >> 6) * 16 + kk * 4 + quad) * 1024 + (n & 63) * 16);
      }
#pragma unroll
      for (int mi = 0; mi < 4; ++mi)
#pragma unroll
        for (int ni = 0; ni < 4; ++ni)
          acc[mi][ni] = __builtin_amdgcn_mfma_f32_16x16x32_bf16(af[mi], bf[ni], acc[mi][ni], 0, 0, 0);
    }
  }

  const int b   = rp / NT_PER_B;
  const int nb0 = (rp % NT_PER_B) * 128;
#pragma unroll
  for (int mi = 0; mi < 4; ++mi) {
    const int co = mtile * 128 + wm * 64 + mi * 16 + quad * 4;  // + reg r
#pragma unroll
    for (int ni = 0; ni < 4; ++ni) {
      const int n = wn * 64 + ni * 16 + l15;
      const int w = n & 63;
      if (w < 56) {
        const int nb = nb0 + n;
        const int h  = nb >> 6;
        floatx4 f = acc[mi][ni];
        const size_t base = (size_t)(b * 256 + co) * 3136 + h * 56 + w;
#pragma unroll
        for (int r = 0; r < 4; ++r)
          out[base + (size_t)r * 3136] = f[r] + fcb[co + r];
      }
    }
  }
}

extern "C" void kernel_launch(void* const* d_in, const int* in_sizes, int n_in,
                              void* d_out, int out_size, void* d_ws, size_t ws_size,
                              hipStream_t stream) {
  const float* x  = (const float*)d_in[0];
  const float* bw = (const float*)d_in[1];
  const float* fw = (const float*)d_in[2];
  const float* fb = (const float*)d_in[3];
  float* out = (float*)d_out;
  char* ws = (char*)d_ws;

  __hip_bfloat16* Wp = (__hip_bfloat16*)(ws + OFF_WP);
  __hip_bfloat16* A2 = (__hip_bfloat16*)(ws + OFF_A2);
  __hip_bfloat16* Xp = (__hip_bfloat16*)(ws + OFF_XP);
  __hip_bfloat16* Y  = (__hip_bfloat16*)(ws + OFF_Y);

  k_wprep<<<dim3(4608), dim3(256), 0, stream>>>(bw, Wp);
  k_a2prep<<<dim3(512), dim3(256), 0, stream>>>(fw, A2);
  k_xprep<<<dim3(14848), dim3(256), 0, stream>>>(x, Xp);
  k_conv1<<<dim3(896), dim3(512), 0, stream>>>(Xp, Wp, Y);
  k_conv2<<<dim3(1792), dim3(256), 0, stream>>>(Y, A2, fb, out);
}